// Round 1
// baseline (844.840 us; speedup 1.0000x reference)
//
#include <hip/hip_runtime.h>

namespace {
constexpr int kB    = 32;
constexpr int kCin  = 256;
constexpr int kCout = 512;
constexpr int kL    = 2048;
constexpr float kEps = 1e-5f;

constexpr int BK = 16;       // K-step
constexpr int MT = 128;      // channel tile
constexpr int NT = 64;       // position tile
constexpr int NBL    = kL / NT;        // 32 n-tiles per batch row
constexpr int NTILES = kB * NBL;       // 1024
constexpr int MTILES = kCout / MT;     // 4
}

// ws layout (floats): [0,512) sum, [512,1024) sumsq, [1024,1536) scale, [1536,2048) shift

// ---------------------------------------------------------------- pass 1: stats
__global__ __launch_bounds__(256) void k_stats(
    const float* __restrict__ x, const float* __restrict__ sw,
    const float* __restrict__ pw_w, const float* __restrict__ pw_b,
    float* __restrict__ stats)
{
    __shared__ __align__(16) float asT[BK][MT];   // pw_w^T tile [k][o]
    __shared__ __align__(16) float zs[BK][NT];    // dw-conv output tile

    const int tid = threadIdx.x;
    const int tx = tid & 15;
    const int ty = tid >> 4;
    const int mt = blockIdx.x & (MTILES - 1);     // fast-varying: L2/L3 reuse of x tile
    const int nt = blockIdx.x >> 2;
    const int b  = nt / NBL;
    const int l0 = (nt % NBL) * NT;
    const int o0 = mt * MT;

    const float w0 = sw[0], w1 = sw[1], w2 = sw[2];
    const float* xb = x + (size_t)b * kCin * kL;

    float acc[8][4];
    #pragma unroll
    for (int i = 0; i < 8; ++i)
        #pragma unroll
        for (int j = 0; j < 4; ++j) acc[i][j] = 0.f;

    const int ar = tid >> 1;          // 0..127 (weight row within tile)
    const int ac = (tid & 1) * 8;     // 0 or 8 (k offset)

    for (int k0 = 0; k0 < kCin; k0 += BK) {
        __syncthreads();
        { // stage pw_w^T
            const float* src = pw_w + (size_t)(o0 + ar) * kCin + k0 + ac;
            float4 v0 = *(const float4*)(src);
            float4 v1 = *(const float4*)(src + 4);
            asT[ac + 0][ar] = v0.x; asT[ac + 1][ar] = v0.y;
            asT[ac + 2][ar] = v0.z; asT[ac + 3][ar] = v0.w;
            asT[ac + 4][ar] = v1.x; asT[ac + 5][ar] = v1.y;
            asT[ac + 6][ar] = v1.z; asT[ac + 7][ar] = v1.w;
        }
        { // stage z tile: z[l] = w0*x[l-4] + w1*x[l-2] + w2*x[l], causal zero-pad
            const int c4 = tx * 4;
            const float* xr = xb + (size_t)(k0 + ty) * kL + l0 + c4;
            float4 cur = *(const float4*)(xr);
            float4 prv;
            if (l0 + c4 >= 4) prv = *(const float4*)(xr - 4);
            else               prv = make_float4(0.f, 0.f, 0.f, 0.f);
            float4 z;
            z.x = fmaf(w0, prv.x, fmaf(w1, prv.z, w2 * cur.x));
            z.y = fmaf(w0, prv.y, fmaf(w1, prv.w, w2 * cur.y));
            z.z = fmaf(w0, prv.z, fmaf(w1, cur.x, w2 * cur.z));
            z.w = fmaf(w0, prv.w, fmaf(w1, cur.y, w2 * cur.w));
            *(float4*)&zs[ty][c4] = z;
        }
        __syncthreads();
        #pragma unroll
        for (int k = 0; k < BK; ++k) {
            const float4 a0 = *(const float4*)&asT[k][ty * 8 + 0];
            const float4 a1 = *(const float4*)&asT[k][ty * 8 + 4];
            const float4 zv = *(const float4*)&zs[k][tx * 4];
            const float av[8] = {a0.x, a0.y, a0.z, a0.w, a1.x, a1.y, a1.z, a1.w};
            const float bv[4] = {zv.x, zv.y, zv.z, zv.w};
            #pragma unroll
            for (int i = 0; i < 8; ++i)
                #pragma unroll
                for (int j = 0; j < 4; ++j)
                    acc[i][j] = fmaf(av[i], bv[j], acc[i][j]);
        }
    }

    // per-channel sum / sumsq, reduce across tx (lane bits 0..3), one atomic per channel
    #pragma unroll
    for (int i = 0; i < 8; ++i) {
        const int o = o0 + ty * 8 + i;
        const float bias = pw_b[o];
        float s = 0.f, q = 0.f;
        #pragma unroll
        for (int j = 0; j < 4; ++j) {
            float y = acc[i][j] + bias;
            s += y;
            q = fmaf(y, y, q);
        }
        #pragma unroll
        for (int m = 1; m <= 8; m <<= 1) {
            s += __shfl_xor(s, m, 64);
            q += __shfl_xor(q, m, 64);
        }
        if (tx == 0) {
            atomicAdd(&stats[o], s);
            atomicAdd(&stats[kCout + o], q);
        }
    }
}

// ---------------------------------------------------------------- pass 2: BN params
__global__ void k_bnparams(float* __restrict__ stats,
                           const float* __restrict__ gamma,
                           const float* __restrict__ beta)
{
    const int o = threadIdx.x;
    if (o < kCout) {
        const float inv_n = 1.0f / (float)(kB * kL);
        const float mean = stats[o] * inv_n;
        const float var  = stats[kCout + o] * inv_n - mean * mean;
        const float sc   = gamma[o] * rsqrtf(var + kEps);
        stats[2 * kCout + o] = sc;
        stats[3 * kCout + o] = beta[o] - mean * sc;
    }
}

// ---------------------------------------------------------------- pass 3: output
__global__ __launch_bounds__(256) void k_out(
    const float* __restrict__ x, const float* __restrict__ sw,
    const float* __restrict__ pw_w, const float* __restrict__ pw_b,
    const float* __restrict__ res_w, const float* __restrict__ res_b,
    const float* __restrict__ stats, float* __restrict__ out)
{
    __shared__ __align__(16) float asP[BK][MT];
    __shared__ __align__(16) float asR[BK][MT];
    __shared__ __align__(16) float zs[BK][NT];
    __shared__ __align__(16) float xs[BK][NT];

    const int tid = threadIdx.x;
    const int tx = tid & 15;
    const int ty = tid >> 4;
    const int mt = blockIdx.x & (MTILES - 1);
    const int nt = blockIdx.x >> 2;
    const int b  = nt / NBL;
    const int l0 = (nt % NBL) * NT;
    const int o0 = mt * MT;

    const float w0 = sw[0], w1 = sw[1], w2 = sw[2];
    const float* xb = x + (size_t)b * kCin * kL;

    float accY[8][4], accR[8][4];
    #pragma unroll
    for (int i = 0; i < 8; ++i)
        #pragma unroll
        for (int j = 0; j < 4; ++j) { accY[i][j] = 0.f; accR[i][j] = 0.f; }

    const int ar = tid >> 1;
    const int ac = (tid & 1) * 8;

    for (int k0 = 0; k0 < kCin; k0 += BK) {
        __syncthreads();
        { // stage both weight tiles (transposed)
            const float* srcP = pw_w  + (size_t)(o0 + ar) * kCin + k0 + ac;
            const float* srcR = res_w + (size_t)(o0 + ar) * kCin + k0 + ac;
            float4 p0 = *(const float4*)(srcP);
            float4 p1 = *(const float4*)(srcP + 4);
            float4 r0 = *(const float4*)(srcR);
            float4 r1 = *(const float4*)(srcR + 4);
            asP[ac + 0][ar] = p0.x; asP[ac + 1][ar] = p0.y;
            asP[ac + 2][ar] = p0.z; asP[ac + 3][ar] = p0.w;
            asP[ac + 4][ar] = p1.x; asP[ac + 5][ar] = p1.y;
            asP[ac + 6][ar] = p1.z; asP[ac + 7][ar] = p1.w;
            asR[ac + 0][ar] = r0.x; asR[ac + 1][ar] = r0.y;
            asR[ac + 2][ar] = r0.z; asR[ac + 3][ar] = r0.w;
            asR[ac + 4][ar] = r1.x; asR[ac + 5][ar] = r1.y;
            asR[ac + 6][ar] = r1.z; asR[ac + 7][ar] = r1.w;
        }
        { // stage x tile + z tile
            const int c4 = tx * 4;
            const float* xr = xb + (size_t)(k0 + ty) * kL + l0 + c4;
            float4 cur = *(const float4*)(xr);
            float4 prv;
            if (l0 + c4 >= 4) prv = *(const float4*)(xr - 4);
            else               prv = make_float4(0.f, 0.f, 0.f, 0.f);
            float4 z;
            z.x = fmaf(w0, prv.x, fmaf(w1, prv.z, w2 * cur.x));
            z.y = fmaf(w0, prv.y, fmaf(w1, prv.w, w2 * cur.y));
            z.z = fmaf(w0, prv.z, fmaf(w1, cur.x, w2 * cur.z));
            z.w = fmaf(w0, prv.w, fmaf(w1, cur.y, w2 * cur.w));
            *(float4*)&zs[ty][c4] = z;
            *(float4*)&xs[ty][c4] = cur;
        }
        __syncthreads();
        #pragma unroll
        for (int k = 0; k < BK; ++k) {
            const float4 p0 = *(const float4*)&asP[k][ty * 8 + 0];
            const float4 p1 = *(const float4*)&asP[k][ty * 8 + 4];
            const float4 r0 = *(const float4*)&asR[k][ty * 8 + 0];
            const float4 r1 = *(const float4*)&asR[k][ty * 8 + 4];
            const float4 zv = *(const float4*)&zs[k][tx * 4];
            const float4 xv = *(const float4*)&xs[k][tx * 4];
            const float pv[8] = {p0.x, p0.y, p0.z, p0.w, p1.x, p1.y, p1.z, p1.w};
            const float rv[8] = {r0.x, r0.y, r0.z, r0.w, r1.x, r1.y, r1.z, r1.w};
            const float zb[4] = {zv.x, zv.y, zv.z, zv.w};
            const float xb4[4] = {xv.x, xv.y, xv.z, xv.w};
            #pragma unroll
            for (int i = 0; i < 8; ++i)
                #pragma unroll
                for (int j = 0; j < 4; ++j) {
                    accY[i][j] = fmaf(pv[i], zb[j], accY[i][j]);
                    accR[i][j] = fmaf(rv[i], xb4[j], accR[i][j]);
                }
        }
    }

    // epilogue: BN + ReLU + residual + ReLU, coalesced float4 stores
    #pragma unroll
    for (int i = 0; i < 8; ++i) {
        const int o = o0 + ty * 8 + i;
        const float sc = stats[2 * kCout + o];
        const float sh = stats[3 * kCout + o];
        const float c1 = fmaf(pw_b[o], sc, sh);   // (y+pw_b)*sc+sh == y*sc + c1
        const float rb = res_b[o];
        float4 v;
        float tmp[4];
        #pragma unroll
        for (int j = 0; j < 4; ++j) {
            float yn = fmaf(accY[i][j], sc, c1);
            yn = fmaxf(yn, 0.f);
            float r = accR[i][j] + rb;
            tmp[j] = fmaxf(yn + r, 0.f);
        }
        v.x = tmp[0]; v.y = tmp[1]; v.z = tmp[2]; v.w = tmp[3];
        *(float4*)(out + ((size_t)b * kCout + o) * kL + l0 + tx * 4) = v;
    }
}

extern "C" void kernel_launch(void* const* d_in, const int* in_sizes, int n_in,
                              void* d_out, int out_size, void* d_ws, size_t ws_size,
                              hipStream_t stream)
{
    (void)in_sizes; (void)n_in; (void)out_size; (void)ws_size;
    const float* x     = (const float*)d_in[0];
    const float* sw    = (const float*)d_in[1];
    const float* pw_w  = (const float*)d_in[2];
    const float* pw_b  = (const float*)d_in[3];
    const float* gamma = (const float*)d_in[4];
    const float* beta  = (const float*)d_in[5];
    const float* res_w = (const float*)d_in[6];
    const float* res_b = (const float*)d_in[7];
    float* out   = (float*)d_out;
    float* stats = (float*)d_ws;

    hipMemsetAsync(stats, 0, 2 * kCout * sizeof(float), stream);
    k_stats<<<dim3(NTILES * MTILES), 256, 0, stream>>>(x, sw, pw_w, pw_b, stats);
    k_bnparams<<<1, kCout, 0, stream>>>(stats, gamma, beta);
    k_out<<<dim3(NTILES * MTILES), 256, 0, stream>>>(x, sw, pw_w, pw_b, res_w, res_b, stats, out);
}

// Round 2
// 438.691 us; speedup vs baseline: 1.9258x; 1.9258x over previous
//
#include <hip/hip_runtime.h>

typedef __attribute__((ext_vector_type(8))) short short8;
typedef __attribute__((ext_vector_type(4))) float floatx4;

namespace {
constexpr int kB = 32, kCin = 256, kCout = 512, kL = 2048;
constexpr float kEps = 1e-5f;
constexpr int MT = 128;                 // o-tile
constexpr int NT = 64;                  // l-tile
constexpr int BK = 32;                  // k-step (one MFMA K)
constexpr int KSTEPS = kCin / BK;       // 8
constexpr int LT = kL / NT;             // 32 l-tiles per batch
constexpr int MTILES = kCout / MT;      // 4
constexpr int GRID = MTILES * LT * kB;  // 4096 blocks
constexpr int BST = 40;                 // Bs row stride in ushorts (32 data + 8 pad -> 80B, kills mod-32 bank aliasing)
constexpr float kInvN = 1.0f / (float)(kB * kL);
}

__device__ inline unsigned short f2bf(float f) {
    union { float f; unsigned u; } v; v.f = f;
    return (unsigned short)((v.u + 0x7fffu + ((v.u >> 16) & 1u)) >> 16);  // RNE
}
__device__ inline unsigned pack2(float lo, float hi) {
    return (unsigned)f2bf(lo) | ((unsigned)f2bf(hi) << 16);
}

// stage 16 consecutive fp32 -> 16 bf16 in LDS (two 16B stores)
__device__ inline void stage_w16(const float* __restrict__ src, unsigned short* __restrict__ dst) {
    float4 v0 = ((const float4*)src)[0];
    float4 v1 = ((const float4*)src)[1];
    float4 v2 = ((const float4*)src)[2];
    float4 v3 = ((const float4*)src)[3];
    union { unsigned short u[8]; short8 v; } a, b;
    a.u[0]=f2bf(v0.x); a.u[1]=f2bf(v0.y); a.u[2]=f2bf(v0.z); a.u[3]=f2bf(v0.w);
    a.u[4]=f2bf(v1.x); a.u[5]=f2bf(v1.y); a.u[6]=f2bf(v1.z); a.u[7]=f2bf(v1.w);
    b.u[0]=f2bf(v2.x); b.u[1]=f2bf(v2.y); b.u[2]=f2bf(v2.z); b.u[3]=f2bf(v2.w);
    b.u[4]=f2bf(v3.x); b.u[5]=f2bf(v3.y); b.u[6]=f2bf(v3.z); b.u[7]=f2bf(v3.w);
    ((short8*)dst)[0] = a.v;
    ((short8*)dst)[1] = b.v;
}

// ws layout (floats): [0,512) sum_raw, [512,1024) sumsq_raw, [1024,1536) scale, [1536,2048) shift

// ---------------------------------------------------------------- pass 1: stats (MFMA GEMM)
__global__ __launch_bounds__(256) void k_stats(
    const float* __restrict__ x, const float* __restrict__ sw,
    const float* __restrict__ pw_w, float* __restrict__ stats)
{
    __shared__ __align__(16) unsigned short As[MT * BK];   // [o][k], 64B rows
    __shared__ __align__(16) unsigned short Bz[NT * BST];  // [l][c], 80B rows
    __shared__ float red[2][4][4][4][2];

    const int tid = threadIdx.x;
    const int lane = tid & 63, wave = tid >> 6;
    const int fr = lane & 15, fq = lane >> 4;
    const int wo = (wave >> 1) * 64, wl = (wave & 1) * 32;

    const int mt = blockIdx.x & (MTILES - 1);
    const int rest = blockIdx.x >> 2;
    const int lt = rest & (LT - 1);
    const int b = rest >> 5;
    const int o0 = mt * MT, l0 = lt * NT;

    const float w0 = sw[0], w1 = sw[1], w2 = sw[2];
    const float* xb = x + (size_t)b * kCin * kL;

    floatx4 acc[4][2];
    #pragma unroll
    for (int mi = 0; mi < 4; ++mi)
        #pragma unroll
        for (int ni = 0; ni < 2; ++ni) acc[mi][ni] = (floatx4){0.f, 0.f, 0.f, 0.f};

    const int sr = tid >> 1, sh_ = (tid & 1) * 16;       // A staging: row, k-half
    const int c2 = (tid & 15) * 2, ll = (tid >> 4) * 4;  // B staging: 2 channels, 4 l
    const bool hasprv = (l0 + ll) >= 4;

    int aOff[4], bOff[2];
    #pragma unroll
    for (int mi = 0; mi < 4; ++mi) aOff[mi] = (wo + mi * 16 + fr) * BK + fq * 8;
    #pragma unroll
    for (int ni = 0; ni < 2; ++ni) bOff[ni] = (wl + ni * 16 + fr) * BST + fq * 8;

    for (int ks = 0; ks < KSTEPS; ++ks) {
        const int k0 = ks * BK;
        __syncthreads();
        stage_w16(pw_w + (size_t)(o0 + sr) * kCin + k0 + sh_, &As[sr * BK + sh_]);
        {
            const float* base = xb + (size_t)(k0 + c2) * kL + l0 + ll;
            float4 cA = *(const float4*)base;
            float4 cB = *(const float4*)(base + kL);
            float4 pA, pB;
            if (hasprv) { pA = *(const float4*)(base - 4); pB = *(const float4*)(base + kL - 4); }
            else { pA = make_float4(0.f,0.f,0.f,0.f); pB = make_float4(0.f,0.f,0.f,0.f); }
            float zA[4], zB[4];
            zA[0] = fmaf(w0, pA.x, fmaf(w1, pA.z, w2 * cA.x));
            zA[1] = fmaf(w0, pA.y, fmaf(w1, pA.w, w2 * cA.y));
            zA[2] = fmaf(w0, pA.z, fmaf(w1, cA.x, w2 * cA.z));
            zA[3] = fmaf(w0, pA.w, fmaf(w1, cA.y, w2 * cA.w));
            zB[0] = fmaf(w0, pB.x, fmaf(w1, pB.z, w2 * cB.x));
            zB[1] = fmaf(w0, pB.y, fmaf(w1, pB.w, w2 * cB.y));
            zB[2] = fmaf(w0, pB.z, fmaf(w1, cB.x, w2 * cB.z));
            zB[3] = fmaf(w0, pB.w, fmaf(w1, cB.y, w2 * cB.w));
            #pragma unroll
            for (int j = 0; j < 4; ++j)
                *(unsigned*)&Bz[(ll + j) * BST + c2] = pack2(zA[j], zB[j]);
        }
        __syncthreads();
        short8 bfr[2];
        #pragma unroll
        for (int ni = 0; ni < 2; ++ni) bfr[ni] = *(const short8*)&Bz[bOff[ni]];
        #pragma unroll
        for (int mi = 0; mi < 4; ++mi) {
            short8 af = *(const short8*)&As[aOff[mi]];
            #pragma unroll
            for (int ni = 0; ni < 2; ++ni)
                acc[mi][ni] = __builtin_amdgcn_mfma_f32_16x16x32_bf16(af, bfr[ni], acc[mi][ni], 0, 0, 0);
        }
    }

    // per-channel sum/sumsq of RAW gemm output (bias folded analytically in k_bnparams)
    float sv[4][4], qv[4][4];
    #pragma unroll
    for (int mi = 0; mi < 4; ++mi)
        #pragma unroll
        for (int r = 0; r < 4; ++r) {
            float a0 = acc[mi][0][r], a1 = acc[mi][1][r];
            float s = a0 + a1;
            float q = fmaf(a0, a0, a1 * a1);
            #pragma unroll
            for (int m = 1; m <= 8; m <<= 1) {
                s += __shfl_xor(s, m, 64);
                q += __shfl_xor(q, m, 64);
            }
            sv[mi][r] = s; qv[mi][r] = q;
        }
    if ((wave & 1) == 1 && fr == 0) {
        #pragma unroll
        for (int mi = 0; mi < 4; ++mi)
            #pragma unroll
            for (int r = 0; r < 4; ++r) {
                red[wave >> 1][mi][r][fq][0] = sv[mi][r];
                red[wave >> 1][mi][r][fq][1] = qv[mi][r];
            }
    }
    __syncthreads();
    if ((wave & 1) == 0 && fr == 0) {
        #pragma unroll
        for (int mi = 0; mi < 4; ++mi)
            #pragma unroll
            for (int r = 0; r < 4; ++r) {
                const int o = o0 + wo + mi * 16 + fq * 4 + r;
                atomicAdd(&stats[o],         sv[mi][r] + red[wave >> 1][mi][r][fq][0]);
                atomicAdd(&stats[kCout + o], qv[mi][r] + red[wave >> 1][mi][r][fq][1]);
            }
    }
}

// ---------------------------------------------------------------- pass 2: BN params
__global__ void k_bnparams(float* __restrict__ stats,
                           const float* __restrict__ gamma,
                           const float* __restrict__ beta)
{
    const int o = threadIdx.x;
    const float s1 = stats[o] * kInvN;          // E[raw]
    const float s2 = stats[kCout + o] * kInvN;  // E[raw^2]
    const float var = s2 - s1 * s1;             // var(y) == var(raw)
    const float sc = gamma[o] * rsqrtf(var + kEps);
    stats[2 * kCout + o] = sc;
    stats[3 * kCout + o] = fmaf(-s1, sc, beta[o]);  // yn = raw*sc + this (pw_b cancels)
}

// ---------------------------------------------------------------- pass 3: dual MFMA GEMM + epilogue
__global__ __launch_bounds__(256) void k_out(
    const float* __restrict__ x, const float* __restrict__ sw,
    const float* __restrict__ pw_w, const float* __restrict__ res_w,
    const float* __restrict__ res_b, const float* __restrict__ stats,
    float* __restrict__ out)
{
    __shared__ __align__(16) unsigned short AsP[MT * BK];
    __shared__ __align__(16) unsigned short AsR[MT * BK];
    __shared__ __align__(16) unsigned short Bz[NT * BST];
    __shared__ __align__(16) unsigned short Bx[NT * BST];

    const int tid = threadIdx.x;
    const int lane = tid & 63, wave = tid >> 6;
    const int fr = lane & 15, fq = lane >> 4;
    const int wo = (wave >> 1) * 64, wl = (wave & 1) * 32;

    const int mt = blockIdx.x & (MTILES - 1);
    const int rest = blockIdx.x >> 2;
    const int lt = rest & (LT - 1);
    const int b = rest >> 5;
    const int o0 = mt * MT, l0 = lt * NT;

    const float w0 = sw[0], w1 = sw[1], w2 = sw[2];
    const float* xb = x + (size_t)b * kCin * kL;

    floatx4 accY[4][2], accR[4][2];
    #pragma unroll
    for (int mi = 0; mi < 4; ++mi)
        #pragma unroll
        for (int ni = 0; ni < 2; ++ni) {
            accY[mi][ni] = (floatx4){0.f, 0.f, 0.f, 0.f};
            accR[mi][ni] = (floatx4){0.f, 0.f, 0.f, 0.f};
        }

    const int sr = tid >> 1, sh_ = (tid & 1) * 16;
    const int c2 = (tid & 15) * 2, ll = (tid >> 4) * 4;
    const bool hasprv = (l0 + ll) >= 4;

    int aOff[4], bOff[2];
    #pragma unroll
    for (int mi = 0; mi < 4; ++mi) aOff[mi] = (wo + mi * 16 + fr) * BK + fq * 8;
    #pragma unroll
    for (int ni = 0; ni < 2; ++ni) bOff[ni] = (wl + ni * 16 + fr) * BST + fq * 8;

    for (int ks = 0; ks < KSTEPS; ++ks) {
        const int k0 = ks * BK;
        __syncthreads();
        stage_w16(pw_w  + (size_t)(o0 + sr) * kCin + k0 + sh_, &AsP[sr * BK + sh_]);
        stage_w16(res_w + (size_t)(o0 + sr) * kCin + k0 + sh_, &AsR[sr * BK + sh_]);
        {
            const float* base = xb + (size_t)(k0 + c2) * kL + l0 + ll;
            float4 cA = *(const float4*)base;
            float4 cB = *(const float4*)(base + kL);
            float4 pA, pB;
            if (hasprv) { pA = *(const float4*)(base - 4); pB = *(const float4*)(base + kL - 4); }
            else { pA = make_float4(0.f,0.f,0.f,0.f); pB = make_float4(0.f,0.f,0.f,0.f); }
            float zA[4], zB[4];
            zA[0] = fmaf(w0, pA.x, fmaf(w1, pA.z, w2 * cA.x));
            zA[1] = fmaf(w0, pA.y, fmaf(w1, pA.w, w2 * cA.y));
            zA[2] = fmaf(w0, pA.z, fmaf(w1, cA.x, w2 * cA.z));
            zA[3] = fmaf(w0, pA.w, fmaf(w1, cA.y, w2 * cA.w));
            zB[0] = fmaf(w0, pB.x, fmaf(w1, pB.z, w2 * cB.x));
            zB[1] = fmaf(w0, pB.y, fmaf(w1, pB.w, w2 * cB.y));
            zB[2] = fmaf(w0, pB.z, fmaf(w1, cB.x, w2 * cB.z));
            zB[3] = fmaf(w0, pB.w, fmaf(w1, cB.y, w2 * cB.w));
            const float xA[4] = {cA.x, cA.y, cA.z, cA.w};
            const float xB[4] = {cB.x, cB.y, cB.z, cB.w};
            #pragma unroll
            for (int j = 0; j < 4; ++j) {
                *(unsigned*)&Bz[(ll + j) * BST + c2] = pack2(zA[j], zB[j]);
                *(unsigned*)&Bx[(ll + j) * BST + c2] = pack2(xA[j], xB[j]);
            }
        }
        __syncthreads();
        short8 bz[2], bx[2];
        #pragma unroll
        for (int ni = 0; ni < 2; ++ni) {
            bz[ni] = *(const short8*)&Bz[bOff[ni]];
            bx[ni] = *(const short8*)&Bx[bOff[ni]];
        }
        #pragma unroll
        for (int mi = 0; mi < 4; ++mi) {
            short8 ap = *(const short8*)&AsP[aOff[mi]];
            short8 ar = *(const short8*)&AsR[aOff[mi]];
            #pragma unroll
            for (int ni = 0; ni < 2; ++ni) {
                accY[mi][ni] = __builtin_amdgcn_mfma_f32_16x16x32_bf16(ap, bz[ni], accY[mi][ni], 0, 0, 0);
                accR[mi][ni] = __builtin_amdgcn_mfma_f32_16x16x32_bf16(ar, bx[ni], accR[mi][ni], 0, 0, 0);
            }
        }
    }

    // epilogue: BN + ReLU + residual + ReLU
    const float* scv = stats + 2 * kCout;
    const float* shv = stats + 3 * kCout;
    #pragma unroll
    for (int mi = 0; mi < 4; ++mi)
        #pragma unroll
        for (int r = 0; r < 4; ++r) {
            const int o = o0 + wo + mi * 16 + fq * 4 + r;
            const float sc = scv[o], sh = shv[o], rb = res_b[o];
            const size_t orow = ((size_t)b * kCout + o) * kL + l0 + wl + fr;
            #pragma unroll
            for (int ni = 0; ni < 2; ++ni) {
                float yn = fmaxf(fmaf(accY[mi][ni][r], sc, sh), 0.f);
                float rr = accR[mi][ni][r] + rb;
                out[orow + ni * 16] = fmaxf(yn + rr, 0.f);
            }
        }
}

extern "C" void kernel_launch(void* const* d_in, const int* in_sizes, int n_in,
                              void* d_out, int out_size, void* d_ws, size_t ws_size,
                              hipStream_t stream)
{
    (void)in_sizes; (void)n_in; (void)out_size; (void)ws_size;
    const float* x     = (const float*)d_in[0];
    const float* sw    = (const float*)d_in[1];
    const float* pw_w  = (const float*)d_in[2];
    const float* gamma = (const float*)d_in[4];
    const float* beta  = (const float*)d_in[5];
    const float* res_w = (const float*)d_in[6];
    const float* res_b = (const float*)d_in[7];
    float* out   = (float*)d_out;
    float* stats = (float*)d_ws;

    hipMemsetAsync(stats, 0, 2 * kCout * sizeof(float), stream);
    k_stats<<<GRID, 256, 0, stream>>>(x, sw, pw_w, stats);
    k_bnparams<<<1, kCout, 0, stream>>>(stats, gamma, beta);
    k_out<<<GRID, 256, 0, stream>>>(x, sw, pw_w, res_w, res_b, stats, out);
}

// Round 3
// 406.563 us; speedup vs baseline: 2.0780x; 1.0790x over previous
//
#include <hip/hip_runtime.h>

typedef __attribute__((ext_vector_type(8))) short short8;
typedef __attribute__((ext_vector_type(4))) float floatx4;

namespace {
constexpr int kB = 32, kCin = 256, kCout = 512, kL = 2048;
constexpr float kEps = 1e-5f;
constexpr float kInvN = 1.0f / (float)(kB * kL);   // 1/65536
constexpr int BK = 32;                   // K-step
constexpr int KSTEPS = kCin / BK;        // 8
constexpr int ST = 44;                   // LDS row stride in ushorts (88 B; gcd(22,32)=2 -> <=2-way)
// k_out tiling: 128 o x 128 l
constexpr int GRID_OUT = 4 * (kL / 128) * kB;      // 4 * 16 * 32 = 2048
// k_gram: chunks of 512 l, 4 quadrants
constexpr int GCHUNK = 512;
constexpr int GKSTEPS = GCHUNK / BK;               // 16
constexpr int GRID_GRAM = 4 * (kB * kL / GCHUNK);  // 4 * 128 = 512
// ws float layout (main path): [0,65536) G | [65536,65792) Sz | [65792,66304) sc | [66304,66816) shift
constexpr int WS_G = 0, WS_SZ = 65536, WS_SC = 65792, WS_SH = 66304;
constexpr size_t WS_NEED = 66816u * 4u;
}

__device__ inline unsigned short f2bf(float f) {
    union { float f; unsigned u; } v; v.f = f;
    return (unsigned short)((v.u + 0x7fffu + ((v.u >> 16) & 1u)) >> 16);  // RNE
}
__device__ inline float bfround(float f) {
    union { unsigned u; float f; } v; v.u = ((unsigned)f2bf(f)) << 16; return v.f;
}
__device__ inline unsigned pack2(float lo, float hi) {
    return (unsigned)f2bf(lo) | ((unsigned)f2bf(hi) << 16);
}

// stage 16 consecutive fp32 -> 16 bf16 into LDS (two b128 stores)
__device__ inline void stage_w16(const float* __restrict__ src, unsigned short* __restrict__ dst) {
    float4 v0 = ((const float4*)src)[0];
    float4 v1 = ((const float4*)src)[1];
    float4 v2 = ((const float4*)src)[2];
    float4 v3 = ((const float4*)src)[3];
    union { unsigned short u[8]; short8 v; } a, b;
    a.u[0]=f2bf(v0.x); a.u[1]=f2bf(v0.y); a.u[2]=f2bf(v0.z); a.u[3]=f2bf(v0.w);
    a.u[4]=f2bf(v1.x); a.u[5]=f2bf(v1.y); a.u[6]=f2bf(v1.z); a.u[7]=f2bf(v1.w);
    b.u[0]=f2bf(v2.x); b.u[1]=f2bf(v2.y); b.u[2]=f2bf(v2.z); b.u[3]=f2bf(v2.w);
    b.u[4]=f2bf(v3.x); b.u[5]=f2bf(v3.y); b.u[6]=f2bf(v3.z); b.u[7]=f2bf(v3.w);
    ((short8*)dst)[0] = a.v;
    ((short8*)dst)[1] = b.v;
}

// ============================================================ k_gram:
// G = Z * Z^T (256x256, K = B*L), Sz = row sums of Z.  Z computed on the fly
// from x (dilated 3-tap, bf16-rounded identically to k_out's Bz tile).
__global__ __launch_bounds__(256, 2) void k_gram(
    const float* __restrict__ x, const float* __restrict__ sw, float* __restrict__ ws)
{
    __shared__ __align__(16) unsigned short Zt[256 * ST];   // 22528 B

    float* __restrict__ G  = ws + WS_G;
    float* __restrict__ Sz = ws + WS_SZ;

    const int tid = threadIdx.x;
    const int lane = tid & 63, wave = tid >> 6;
    const int fr = lane & 15, fq = lane >> 4;

    const int quad = blockIdx.x & 3;
    const int chunk = blockIdx.x >> 2;
    const int qm = (quad >> 1) * 128, qn = (quad & 1) * 128;
    const int b = chunk >> 2;              // 4 chunks of 512 per batch row
    const int l0 = (chunk & 3) * GCHUNK;
    const bool dosz = (quad == 0);         // quad 0 stages all 256 rows once per chunk

    const float w0 = sw[0], w1 = sw[1], w2 = sw[2];
    const float* xb = x + (size_t)b * kCin * kL;

    floatx4 acc[4][4];
    #pragma unroll
    for (int mi = 0; mi < 4; ++mi)
        #pragma unroll
        for (int ni = 0; ni < 4; ++ni) acc[mi][ni] = (floatx4){0.f, 0.f, 0.f, 0.f};

    const int cr = tid >> 3;               // 0..31: row within a 32-row pass
    const int loff = (tid & 7) * 4;        // 0..28: l within 32
    float sz[8] = {0.f,0.f,0.f,0.f,0.f,0.f,0.f,0.f};

    int aOff[4], bOff[4];
    #pragma unroll
    for (int mi = 0; mi < 4; ++mi) aOff[mi] = (qm + (wave >> 1) * 64 + mi * 16 + fr) * ST + fq * 8;
    #pragma unroll
    for (int ni = 0; ni < 4; ++ni) bOff[ni] = (qn + (wave & 1) * 64 + ni * 16 + fr) * ST + fq * 8;

    for (int ks = 0; ks < GKSTEPS; ++ks) {
        const int lk = l0 + ks * BK;
        const bool hasprv = (lk + loff) >= 4;
        __syncthreads();
        #pragma unroll
        for (int p = 0; p < 8; ++p) {
            const int c = p * 32 + cr;
            const float* bp = xb + (size_t)c * kL + lk + loff;
            float4 cur = *(const float4*)bp;
            float4 prv = hasprv ? *(const float4*)(bp - 4) : make_float4(0.f,0.f,0.f,0.f);
            float z0 = fmaf(w0, prv.x, fmaf(w1, prv.z, w2 * cur.x));
            float z1 = fmaf(w0, prv.y, fmaf(w1, prv.w, w2 * cur.y));
            float z2 = fmaf(w0, prv.z, fmaf(w1, cur.x, w2 * cur.z));
            float z3 = fmaf(w0, prv.w, fmaf(w1, cur.y, w2 * cur.w));
            *(unsigned*)&Zt[c * ST + loff]     = pack2(z0, z1);
            *(unsigned*)&Zt[c * ST + loff + 2] = pack2(z2, z3);
            if (dosz) sz[p] += (z0 + z1) + (z2 + z3);
        }
        __syncthreads();
        short8 bf_[4];
        #pragma unroll
        for (int ni = 0; ni < 4; ++ni) bf_[ni] = *(const short8*)&Zt[bOff[ni]];
        #pragma unroll
        for (int mi = 0; mi < 4; ++mi) {
            short8 af = *(const short8*)&Zt[aOff[mi]];
            #pragma unroll
            for (int ni = 0; ni < 4; ++ni)
                acc[mi][ni] = __builtin_amdgcn_mfma_f32_16x16x32_bf16(af, bf_[ni], acc[mi][ni], 0, 0, 0);
        }
    }

    // accumulate partial G (coalesced 16-lane runs)
    #pragma unroll
    for (int mi = 0; mi < 4; ++mi) {
        const int growb = qm + (wave >> 1) * 64 + mi * 16 + fq * 4;
        #pragma unroll
        for (int ni = 0; ni < 4; ++ni) {
            const int gcol = qn + (wave & 1) * 64 + ni * 16 + fr;
            #pragma unroll
            for (int r = 0; r < 4; ++r)
                atomicAdd(&G[(growb + r) * 256 + gcol], acc[mi][ni][r]);
        }
    }
    // Sz: bf16 z row sums (quad 0 only; shuffle over the 8 lanes sharing a row)
    if (dosz) {
        #pragma unroll
        for (int p = 0; p < 8; ++p) {
            float s = sz[p];
            s += __shfl_xor(s, 1, 64);
            s += __shfl_xor(s, 2, 64);
            s += __shfl_xor(s, 4, 64);
            if ((lane & 7) == 0) atomicAdd(&Sz[p * 32 + cr], s);
        }
    }
}

// ============================================================ BN params from Gram:
// mean[o] = (w_bf[o,:] . Sz)/N ; E[y^2][o] = (w_bf[o,:] G w_bf[o,:]^T)/N
__global__ __launch_bounds__(256) void k_bnparams_g(
    const float* __restrict__ ws, const float* __restrict__ pw_w,
    const float* __restrict__ gamma, const float* __restrict__ beta,
    float* __restrict__ sc_out, float* __restrict__ sh_out)
{
    __shared__ float t[256];
    __shared__ float redq[4], redm[4];
    const float* G  = ws + WS_G;
    const float* Sz = ws + WS_SZ;

    const int o = blockIdx.x, c = threadIdx.x;
    const int lane = c & 63, wave = c >> 6;
    t[c] = bfround(pw_w[(size_t)o * kCin + c]);
    __syncthreads();
    const float myt = t[c];
    float q = 0.f;
    #pragma unroll 4
    for (int j = 0; j < 256; ++j)
        q = fmaf(t[j], G[j * 256 + c], q);
    q *= myt;
    float m = myt * Sz[c];
    #pragma unroll
    for (int off = 1; off <= 32; off <<= 1) {
        q += __shfl_xor(q, off, 64);
        m += __shfl_xor(m, off, 64);
    }
    if (lane == 0) { redq[wave] = q; redm[wave] = m; }
    __syncthreads();
    if (c == 0) {
        const float qt = (redq[0] + redq[1]) + (redq[2] + redq[3]);
        const float mt = (redm[0] + redm[1]) + (redm[2] + redm[3]);
        const float mean = mt * kInvN;
        const float e2 = qt * kInvN;
        const float var = e2 - mean * mean;
        const float s = gamma[o] * rsqrtf(var + kEps);
        sc_out[o] = s;
        sh_out[o] = fmaf(-mean, s, beta[o]);
    }
}

// ============================================================ fallback stats (R2 path, used if ws too small)
__global__ __launch_bounds__(256) void k_stats_fb(
    const float* __restrict__ x, const float* __restrict__ sw,
    const float* __restrict__ pw_w, float* __restrict__ stats)
{
    __shared__ __align__(16) unsigned short As[128 * 32];
    __shared__ __align__(16) unsigned short Bz[64 * 40];
    __shared__ float red[2][4][4][4][2];

    const int tid = threadIdx.x;
    const int lane = tid & 63, wave = tid >> 6;
    const int fr = lane & 15, fq = lane >> 4;
    const int wo = (wave >> 1) * 64, wl = (wave & 1) * 32;
    const int mt = blockIdx.x & 3;
    const int rest = blockIdx.x >> 2;
    const int lt = rest & 31;
    const int b = rest >> 5;
    const int o0 = mt * 128, l0 = lt * 64;
    const float w0 = sw[0], w1 = sw[1], w2 = sw[2];
    const float* xb = x + (size_t)b * kCin * kL;

    floatx4 acc[4][2];
    #pragma unroll
    for (int mi = 0; mi < 4; ++mi)
        #pragma unroll
        for (int ni = 0; ni < 2; ++ni) acc[mi][ni] = (floatx4){0.f, 0.f, 0.f, 0.f};

    const int sr = tid >> 1, sh_ = (tid & 1) * 16;
    const int c2 = (tid & 15) * 2, ll = (tid >> 4) * 4;
    const bool hasprv = (l0 + ll) >= 4;
    int aOff[4], bOff[2];
    #pragma unroll
    for (int mi = 0; mi < 4; ++mi) aOff[mi] = (wo + mi * 16 + fr) * 32 + fq * 8;
    #pragma unroll
    for (int ni = 0; ni < 2; ++ni) bOff[ni] = (wl + ni * 16 + fr) * 40 + fq * 8;

    for (int ks = 0; ks < KSTEPS; ++ks) {
        const int k0 = ks * BK;
        __syncthreads();
        stage_w16(pw_w + (size_t)(o0 + sr) * kCin + k0 + sh_, &As[sr * 32 + sh_]);
        {
            const float* base = xb + (size_t)(k0 + c2) * kL + l0 + ll;
            float4 cA = *(const float4*)base;
            float4 cB = *(const float4*)(base + kL);
            float4 pA, pB;
            if (hasprv) { pA = *(const float4*)(base - 4); pB = *(const float4*)(base + kL - 4); }
            else { pA = make_float4(0.f,0.f,0.f,0.f); pB = make_float4(0.f,0.f,0.f,0.f); }
            float zA[4], zB[4];
            zA[0] = fmaf(w0, pA.x, fmaf(w1, pA.z, w2 * cA.x));
            zA[1] = fmaf(w0, pA.y, fmaf(w1, pA.w, w2 * cA.y));
            zA[2] = fmaf(w0, pA.z, fmaf(w1, cA.x, w2 * cA.z));
            zA[3] = fmaf(w0, pA.w, fmaf(w1, cA.y, w2 * cA.w));
            zB[0] = fmaf(w0, pB.x, fmaf(w1, pB.z, w2 * cB.x));
            zB[1] = fmaf(w0, pB.y, fmaf(w1, pB.w, w2 * cB.y));
            zB[2] = fmaf(w0, pB.z, fmaf(w1, cB.x, w2 * cB.z));
            zB[3] = fmaf(w0, pB.w, fmaf(w1, cB.y, w2 * cB.w));
            #pragma unroll
            for (int j = 0; j < 4; ++j)
                *(unsigned*)&Bz[(ll + j) * 40 + c2] = pack2(zA[j], zB[j]);
        }
        __syncthreads();
        short8 bfr[2];
        #pragma unroll
        for (int ni = 0; ni < 2; ++ni) bfr[ni] = *(const short8*)&Bz[bOff[ni]];
        #pragma unroll
        for (int mi = 0; mi < 4; ++mi) {
            short8 af = *(const short8*)&As[aOff[mi]];
            #pragma unroll
            for (int ni = 0; ni < 2; ++ni)
                acc[mi][ni] = __builtin_amdgcn_mfma_f32_16x16x32_bf16(af, bfr[ni], acc[mi][ni], 0, 0, 0);
        }
    }
    float sv[4][4], qv[4][4];
    #pragma unroll
    for (int mi = 0; mi < 4; ++mi)
        #pragma unroll
        for (int r = 0; r < 4; ++r) {
            float a0 = acc[mi][0][r], a1 = acc[mi][1][r];
            float s = a0 + a1;
            float q = fmaf(a0, a0, a1 * a1);
            #pragma unroll
            for (int m = 1; m <= 8; m <<= 1) {
                s += __shfl_xor(s, m, 64);
                q += __shfl_xor(q, m, 64);
            }
            sv[mi][r] = s; qv[mi][r] = q;
        }
    if ((wave & 1) == 1 && fr == 0) {
        #pragma unroll
        for (int mi = 0; mi < 4; ++mi)
            #pragma unroll
            for (int r = 0; r < 4; ++r) {
                red[wave >> 1][mi][r][fq][0] = sv[mi][r];
                red[wave >> 1][mi][r][fq][1] = qv[mi][r];
            }
    }
    __syncthreads();
    if ((wave & 1) == 0 && fr == 0) {
        #pragma unroll
        for (int mi = 0; mi < 4; ++mi)
            #pragma unroll
            for (int r = 0; r < 4; ++r) {
                const int o = o0 + wo + mi * 16 + fq * 4 + r;
                atomicAdd(&stats[o],         sv[mi][r] + red[wave >> 1][mi][r][fq][0]);
                atomicAdd(&stats[kCout + o], qv[mi][r] + red[wave >> 1][mi][r][fq][1]);
            }
    }
}

__global__ void k_bnparams_fb(float* __restrict__ stats,
                              const float* __restrict__ gamma,
                              const float* __restrict__ beta)
{
    const int o = threadIdx.x;
    const float s1 = stats[o] * kInvN;
    const float s2 = stats[kCout + o] * kInvN;
    const float var = s2 - s1 * s1;
    const float sc = gamma[o] * rsqrtf(var + kEps);
    stats[2 * kCout + o] = sc;
    stats[3 * kCout + o] = fmaf(-s1, sc, beta[o]);
}

// ============================================================ pass 3: 128x128 dual GEMM + fused epilogue
__global__ __launch_bounds__(256, 2) void k_out(
    const float* __restrict__ x, const float* __restrict__ sw,
    const float* __restrict__ pw_w, const float* __restrict__ res_w,
    const float* __restrict__ res_b, const float* __restrict__ sc_arr,
    const float* __restrict__ sh_arr, float* __restrict__ out)
{
    __shared__ __align__(16) unsigned short AsP[128 * ST];
    __shared__ __align__(16) unsigned short AsR[128 * ST];
    __shared__ __align__(16) unsigned short Bz[128 * ST];
    __shared__ __align__(16) unsigned short Bx[128 * ST];

    const int tid = threadIdx.x;
    const int lane = tid & 63, wave = tid >> 6;
    const int fr = lane & 15, fq = lane >> 4;
    const int wo = (wave >> 1) * 64;   // o-half within 128
    const int wl = (wave & 1) * 64;    // l-half within 128

    const int mt = blockIdx.x & 3;
    const int rest = blockIdx.x >> 2;
    const int lt = rest & 15;
    const int b = rest >> 4;
    const int o0 = mt * 128, l0 = lt * 128;

    const float w0 = sw[0], w1 = sw[1], w2 = sw[2];
    const float* xb = x + (size_t)b * kCin * kL;

    floatx4 accY[4][4], accR[4][4];
    #pragma unroll
    for (int mi = 0; mi < 4; ++mi)
        #pragma unroll
        for (int ni = 0; ni < 4; ++ni) {
            accY[mi][ni] = (floatx4){0.f, 0.f, 0.f, 0.f};
            accR[mi][ni] = (floatx4){0.f, 0.f, 0.f, 0.f};
        }

    const int sr = tid >> 1, sh_ = (tid & 1) * 16;   // A staging
    const int c2 = (tid & 15) * 2;                   // B staging: channel pair
    const int ll = (tid >> 4) * 8;                   // B staging: 8 l positions
    const bool hasprv = (l0 + ll) >= 4;

    int aOff[4], bOff[4];
    #pragma unroll
    for (int mi = 0; mi < 4; ++mi) aOff[mi] = (wo + mi * 16 + fr) * ST + fq * 8;
    #pragma unroll
    for (int ni = 0; ni < 4; ++ni) bOff[ni] = (wl + ni * 16 + fr) * ST + fq * 8;

    for (int ks = 0; ks < KSTEPS; ++ks) {
        const int k0 = ks * BK;
        __syncthreads();
        stage_w16(pw_w  + (size_t)(o0 + sr) * kCin + k0 + sh_, &AsP[sr * ST + sh_]);
        stage_w16(res_w + (size_t)(o0 + sr) * kCin + k0 + sh_, &AsR[sr * ST + sh_]);
        {
            const float* base0 = xb + (size_t)(k0 + c2) * kL + l0 + ll;
            const float* base1 = base0 + kL;
            float4 pa = hasprv ? *(const float4*)(base0 - 4) : make_float4(0.f,0.f,0.f,0.f);
            float4 a0 = *(const float4*)(base0);
            float4 a1 = *(const float4*)(base0 + 4);
            float4 pb = hasprv ? *(const float4*)(base1 - 4) : make_float4(0.f,0.f,0.f,0.f);
            float4 b0 = *(const float4*)(base1);
            float4 b1 = *(const float4*)(base1 + 4);
            float A[12] = {pa.x,pa.y,pa.z,pa.w, a0.x,a0.y,a0.z,a0.w, a1.x,a1.y,a1.z,a1.w};
            float Bv[12] = {pb.x,pb.y,pb.z,pb.w, b0.x,b0.y,b0.z,b0.w, b1.x,b1.y,b1.z,b1.w};
            #pragma unroll
            for (int j = 0; j < 8; ++j) {
                float zA = fmaf(w0, A[j],  fmaf(w1, A[j + 2],  w2 * A[j + 4]));
                float zB = fmaf(w0, Bv[j], fmaf(w1, Bv[j + 2], w2 * Bv[j + 4]));
                *(unsigned*)&Bz[(ll + j) * ST + c2] = pack2(zA, zB);
                *(unsigned*)&Bx[(ll + j) * ST + c2] = pack2(A[j + 4], Bv[j + 4]);
            }
        }
        __syncthreads();
        short8 vz[4], vx[4];
        #pragma unroll
        for (int ni = 0; ni < 4; ++ni) {
            vz[ni] = *(const short8*)&Bz[bOff[ni]];
            vx[ni] = *(const short8*)&Bx[bOff[ni]];
        }
        #pragma unroll
        for (int mi = 0; mi < 4; ++mi) {
            short8 ap = *(const short8*)&AsP[aOff[mi]];
            short8 ar = *(const short8*)&AsR[aOff[mi]];
            #pragma unroll
            for (int ni = 0; ni < 4; ++ni) {
                accY[mi][ni] = __builtin_amdgcn_mfma_f32_16x16x32_bf16(ap, vz[ni], accY[mi][ni], 0, 0, 0);
                accR[mi][ni] = __builtin_amdgcn_mfma_f32_16x16x32_bf16(ar, vx[ni], accR[mi][ni], 0, 0, 0);
            }
        }
    }

    // epilogue: BN + ReLU + residual + ReLU
    #pragma unroll
    for (int mi = 0; mi < 4; ++mi)
        #pragma unroll
        for (int r = 0; r < 4; ++r) {
            const int o = o0 + wo + mi * 16 + fq * 4 + r;
            const float sc = sc_arr[o], sh = sh_arr[o], rb = res_b[o];
            const size_t orow = ((size_t)b * kCout + o) * kL + l0 + wl + fr;
            #pragma unroll
            for (int ni = 0; ni < 4; ++ni) {
                float yn = fmaxf(fmaf(accY[mi][ni][r], sc, sh), 0.f);
                float rr = accR[mi][ni][r] + rb;
                out[orow + ni * 16] = fmaxf(yn + rr, 0.f);
            }
        }
}

extern "C" void kernel_launch(void* const* d_in, const int* in_sizes, int n_in,
                              void* d_out, int out_size, void* d_ws, size_t ws_size,
                              hipStream_t stream)
{
    (void)in_sizes; (void)n_in; (void)out_size;
    const float* x     = (const float*)d_in[0];
    const float* sw    = (const float*)d_in[1];
    const float* pw_w  = (const float*)d_in[2];
    const float* gamma = (const float*)d_in[4];
    const float* beta  = (const float*)d_in[5];
    const float* res_w = (const float*)d_in[6];
    const float* res_b = (const float*)d_in[7];
    float* out = (float*)d_out;
    float* wsf = (float*)d_ws;

    if (ws_size >= WS_NEED) {
        hipMemsetAsync(wsf, 0, (WS_SC) * sizeof(float), stream);  // zero G + Sz
        k_gram<<<GRID_GRAM, 256, 0, stream>>>(x, sw, wsf);
        k_bnparams_g<<<kCout, 256, 0, stream>>>(wsf, pw_w, gamma, beta, wsf + WS_SC, wsf + WS_SH);
        k_out<<<GRID_OUT, 256, 0, stream>>>(x, sw, pw_w, res_w, res_b,
                                            wsf + WS_SC, wsf + WS_SH, out);
    } else {
        hipMemsetAsync(wsf, 0, 2 * kCout * sizeof(float), stream);
        k_stats_fb<<<4096, 256, 0, stream>>>(x, sw, pw_w, wsf);
        k_bnparams_fb<<<1, kCout, 0, stream>>>(wsf, gamma, beta);
        k_out<<<GRID_OUT, 256, 0, stream>>>(x, sw, pw_w, res_w, res_b,
                                            wsf + 2 * kCout, wsf + 3 * kCout, out);
    }
}

// Round 4
// 333.722 us; speedup vs baseline: 2.5316x; 1.2183x over previous
//
#include <hip/hip_runtime.h>

typedef __attribute__((ext_vector_type(8))) short short8;
typedef __attribute__((ext_vector_type(4))) float floatx4;

namespace {
constexpr int kB = 32, kCin = 256, kCout = 512, kL = 2048;
constexpr float kEps = 1e-5f;
constexpr float kInvN = 1.0f / (float)(kB * kL);   // 1/65536
constexpr int kKtot = kB * kL;                     // 65536
constexpr int BK = 32;
constexpr int KSTEPS = kCin / BK;                  // 8
constexpr int ST = 44;                             // padded LDS row stride (ushorts) for k_out
constexpr int GRID_OUT = 4 * (kL / 128) * kB;      // 2048

// ---- new-path ws layout (floats) ----
constexpr size_t W2_ZC    = 0;          // ushort Zc[256][65536]  -> 8388608 floats
constexpr size_t W2_GPART = 8388608;    // float Gpart[512][16384] -> 8388608 floats
constexpr size_t W2_G     = 16777216;   // float G[256*256]
constexpr size_t W2_SZ    = 16842752;   // float Sz[256]
constexpr size_t W2_SC    = 16843008;   // float sc[512]
constexpr size_t W2_SH    = 16843520;   // float sh[512]
constexpr size_t W2_BYTES = 16844032ull * 4ull;    // ~64.3 MB

// ---- fallback (R3) ws layout (floats) ----
constexpr size_t WF_G = 0, WF_SZ = 65536, WF_SC = 65792, WF_SH = 66304;
constexpr size_t WF_BYTES = 66816ull * 4ull;
}

__device__ inline unsigned short f2bf(float f) {
    union { float f; unsigned u; } v; v.f = f;
    return (unsigned short)((v.u + 0x7fffu + ((v.u >> 16) & 1u)) >> 16);  // RNE
}
__device__ inline float bfround(float f) {
    union { unsigned u; float f; } v; v.u = ((unsigned)f2bf(f)) << 16; return v.f;
}
__device__ inline unsigned pack2(float lo, float hi) {
    return (unsigned)f2bf(lo) | ((unsigned)f2bf(hi) << 16);
}
// async 16B global->LDS (lane i lands at lds_base + i*16)
__device__ inline void cp16(const void* g, void* l) {
    __builtin_amdgcn_global_load_lds(
        (const __attribute__((address_space(1))) unsigned int*)g,
        (__attribute__((address_space(3))) unsigned int*)l, 16, 0, 0);
}

// ============================================================ prep: x -> Zc bf16 [c][b*L], + Sz sums
__global__ __launch_bounds__(256, 4) void k_prepc(
    const float* __restrict__ x, const float* __restrict__ sw,
    unsigned short* __restrict__ Zc, float* __restrict__ Sz)
{
    __shared__ float wred[4];
    const int tid = threadIdx.x;
    const int lane = tid & 63, wave = tid >> 6;
    const int c = blockIdx.x >> 5;   // 0..255
    const int b = blockIdx.x & 31;   // 0..31
    const float w0 = sw[0], w1 = sw[1], w2 = sw[2];
    const int l = tid * 8;
    const float* xr = x + ((size_t)b * kCin + c) * kL + l;
    float4 c0 = *(const float4*)xr;
    float4 c1 = *(const float4*)(xr + 4);
    float4 pv = (l >= 4) ? *(const float4*)(xr - 4) : make_float4(0.f, 0.f, 0.f, 0.f);
    float V[12] = {pv.x,pv.y,pv.z,pv.w, c0.x,c0.y,c0.z,c0.w, c1.x,c1.y,c1.z,c1.w};
    union { unsigned short u[8]; short8 v; } o;
    float s = 0.f;
    #pragma unroll
    for (int j = 0; j < 8; ++j) {
        float z = fmaf(w0, V[j], fmaf(w1, V[j + 2], w2 * V[j + 4]));
        o.u[j] = f2bf(z);
        s += z;
    }
    *(short8*)(Zc + ((size_t)c << 16) + b * kL + l) = o.v;
    #pragma unroll
    for (int m = 1; m <= 32; m <<= 1) s += __shfl_xor(s, m, 64);
    if (lane == 0) wred[wave] = s;
    __syncthreads();
    if (tid == 0) atomicAdd(&Sz[c], (wred[0] + wred[1]) + (wred[2] + wred[3]));
}

// ============================================================ Gram GEMM: Gpart[h*4+q] = Zq_m * Zq_n^T over 512-k chunk
__global__ __launch_bounds__(256, 3) void k_gram2(
    const unsigned short* __restrict__ Zc, float* __restrict__ Gpart)
{
    __shared__ __align__(16) unsigned short Zm[128 * 32];
    __shared__ __align__(16) unsigned short Zn[128 * 32];

    const int tid = threadIdx.x;
    const int lane = tid & 63, wave = tid >> 6;
    const int fr = lane & 15, fq = lane >> 4;
    const int q = blockIdx.x & 3;
    const int h = blockIdx.x >> 2;         // 0..127, 512 k each
    const int qm = (q >> 1) * 128, qn = (q & 1) * 128;
    const int wm = (wave >> 1) * 64, wn = (wave & 1) * 64;

    const int srow = wave * 32 + (lane >> 2);       // staging row within 128 (first 16-row issue)
    const size_t kbase = (size_t)h * 512 + (lane & 3) * 8;
    const unsigned short* gm0 = Zc + (size_t)(qm + srow) * kKtot + kbase;
    const unsigned short* gm1 = gm0 + (size_t)16 * kKtot;
    const unsigned short* gn0 = Zc + (size_t)(qn + srow) * kKtot + kbase;
    const unsigned short* gn1 = gn0 + (size_t)16 * kKtot;
    unsigned short* lm0 = &Zm[(wave * 32) * 32];
    unsigned short* lm1 = &Zm[(wave * 32 + 16) * 32];
    unsigned short* ln0 = &Zn[(wave * 32) * 32];
    unsigned short* ln1 = &Zn[(wave * 32 + 16) * 32];

    floatx4 acc[4][4];
    #pragma unroll
    for (int mi = 0; mi < 4; ++mi)
        #pragma unroll
        for (int ni = 0; ni < 4; ++ni) acc[mi][ni] = (floatx4){0.f, 0.f, 0.f, 0.f};

    for (int ks = 0; ks < 16; ++ks) {
        __syncthreads();
        cp16(gm0, lm0); cp16(gm1, lm1);
        cp16(gn0, ln0); cp16(gn1, ln1);
        gm0 += 32; gm1 += 32; gn0 += 32; gn1 += 32;
        __syncthreads();
        short8 bfp[4];
        #pragma unroll
        for (int ni = 0; ni < 4; ++ni)
            bfp[ni] = *(const short8*)&Zn[(wn + ni * 16 + fr) * 32 + fq * 8];
        #pragma unroll
        for (int mi = 0; mi < 4; ++mi) {
            short8 af = *(const short8*)&Zm[(wm + mi * 16 + fr) * 32 + fq * 8];
            #pragma unroll
            for (int ni = 0; ni < 4; ++ni)
                acc[mi][ni] = __builtin_amdgcn_mfma_f32_16x16x32_bf16(af, bfp[ni], acc[mi][ni], 0, 0, 0);
        }
    }

    float* gp = Gpart + (size_t)blockIdx.x * 16384;
    #pragma unroll
    for (int mi = 0; mi < 4; ++mi)
        #pragma unroll
        for (int ni = 0; ni < 4; ++ni) {
            const int col = wn + ni * 16 + fr;
            #pragma unroll
            for (int r = 0; r < 4; ++r)
                gp[(wm + mi * 16 + fq * 4 + r) * 128 + col] = acc[mi][ni][r];
        }
}

// ============================================================ reduce Gpart -> G
__global__ __launch_bounds__(256) void k_gred(const float* __restrict__ Gpart, float* __restrict__ G)
{
    const int q = blockIdx.x >> 6;
    const int e = (blockIdx.x & 63) * 256 + threadIdx.x;   // 0..16383
    const int qm = (q >> 1) * 128, qn = (q & 1) * 128;
    float s0 = 0.f, s1 = 0.f, s2 = 0.f, s3 = 0.f;
    const float* p = Gpart + e;
    #pragma unroll 4
    for (int hh = 0; hh < 128; hh += 4) {
        s0 += p[(size_t)((hh + 0) * 4 + q) * 16384];
        s1 += p[(size_t)((hh + 1) * 4 + q) * 16384];
        s2 += p[(size_t)((hh + 2) * 4 + q) * 16384];
        s3 += p[(size_t)((hh + 3) * 4 + q) * 16384];
    }
    G[(qm + (e >> 7)) * 256 + qn + (e & 127)] = (s0 + s1) + (s2 + s3);
}

// ============================================================ BN params: mean = w.Sz/N, E[y2] = wGw/N
__global__ __launch_bounds__(256) void k_bnp(
    const float* __restrict__ G, const float* __restrict__ Sz,
    const float* __restrict__ pw_w, const float* __restrict__ gamma,
    const float* __restrict__ beta, float* __restrict__ sc_out, float* __restrict__ sh_out)
{
    __shared__ float t[256];
    __shared__ float redq[4], redm[4];
    const int o = blockIdx.x, c = threadIdx.x;
    const int lane = c & 63, wave = c >> 6;
    t[c] = bfround(pw_w[(size_t)o * kCin + c]);
    __syncthreads();
    const float myt = t[c];
    float q = 0.f;
    #pragma unroll 4
    for (int j = 0; j < 256; ++j)
        q = fmaf(t[j], G[j * 256 + c], q);
    q *= myt;
    float m = myt * Sz[c];
    #pragma unroll
    for (int off = 1; off <= 32; off <<= 1) {
        q += __shfl_xor(q, off, 64);
        m += __shfl_xor(m, off, 64);
    }
    if (lane == 0) { redq[wave] = q; redm[wave] = m; }
    __syncthreads();
    if (c == 0) {
        const float qt = (redq[0] + redq[1]) + (redq[2] + redq[3]);
        const float mt = (redm[0] + redm[1]) + (redm[2] + redm[3]);
        const float mean = mt * kInvN;
        const float var = qt * kInvN - mean * mean;
        const float s = gamma[o] * rsqrtf(var + kEps);
        sc_out[o] = s;
        sh_out[o] = fmaf(-mean, s, beta[o]);
    }
}

// ============================================================ fallback gram (R3 VALU version)
__global__ __launch_bounds__(256, 2) void k_gram_fb(
    const float* __restrict__ x, const float* __restrict__ sw,
    float* __restrict__ G, float* __restrict__ Sz)
{
    __shared__ __align__(16) unsigned short Zt[256 * ST];
    const int tid = threadIdx.x;
    const int lane = tid & 63, wave = tid >> 6;
    const int fr = lane & 15, fq = lane >> 4;
    const int quad = blockIdx.x & 3;
    const int chunk = blockIdx.x >> 2;
    const int qm = (quad >> 1) * 128, qn = (quad & 1) * 128;
    const int b = chunk >> 2;
    const int l0 = (chunk & 3) * 512;
    const bool dosz = (quad == 0);
    const float w0 = sw[0], w1 = sw[1], w2 = sw[2];
    const float* xb = x + (size_t)b * kCin * kL;

    floatx4 acc[4][4];
    #pragma unroll
    for (int mi = 0; mi < 4; ++mi)
        #pragma unroll
        for (int ni = 0; ni < 4; ++ni) acc[mi][ni] = (floatx4){0.f, 0.f, 0.f, 0.f};

    const int cr = tid >> 3;
    const int loff = (tid & 7) * 4;
    float sz[8] = {0.f,0.f,0.f,0.f,0.f,0.f,0.f,0.f};
    int aOff[4], bOff[4];
    #pragma unroll
    for (int mi = 0; mi < 4; ++mi) aOff[mi] = (qm + (wave >> 1) * 64 + mi * 16 + fr) * ST + fq * 8;
    #pragma unroll
    for (int ni = 0; ni < 4; ++ni) bOff[ni] = (qn + (wave & 1) * 64 + ni * 16 + fr) * ST + fq * 8;

    for (int ks = 0; ks < 16; ++ks) {
        const int lk = l0 + ks * BK;
        const bool hasprv = (lk + loff) >= 4;
        __syncthreads();
        #pragma unroll
        for (int p = 0; p < 8; ++p) {
            const int c = p * 32 + cr;
            const float* bp = xb + (size_t)c * kL + lk + loff;
            float4 cur = *(const float4*)bp;
            float4 prv = hasprv ? *(const float4*)(bp - 4) : make_float4(0.f,0.f,0.f,0.f);
            float z0 = fmaf(w0, prv.x, fmaf(w1, prv.z, w2 * cur.x));
            float z1 = fmaf(w0, prv.y, fmaf(w1, prv.w, w2 * cur.y));
            float z2 = fmaf(w0, prv.z, fmaf(w1, cur.x, w2 * cur.z));
            float z3 = fmaf(w0, prv.w, fmaf(w1, cur.y, w2 * cur.w));
            *(unsigned*)&Zt[c * ST + loff]     = pack2(z0, z1);
            *(unsigned*)&Zt[c * ST + loff + 2] = pack2(z2, z3);
            if (dosz) sz[p] += (z0 + z1) + (z2 + z3);
        }
        __syncthreads();
        short8 bf_[4];
        #pragma unroll
        for (int ni = 0; ni < 4; ++ni) bf_[ni] = *(const short8*)&Zt[bOff[ni]];
        #pragma unroll
        for (int mi = 0; mi < 4; ++mi) {
            short8 af = *(const short8*)&Zt[aOff[mi]];
            #pragma unroll
            for (int ni = 0; ni < 4; ++ni)
                acc[mi][ni] = __builtin_amdgcn_mfma_f32_16x16x32_bf16(af, bf_[ni], acc[mi][ni], 0, 0, 0);
        }
    }
    #pragma unroll
    for (int mi = 0; mi < 4; ++mi) {
        const int growb = qm + (wave >> 1) * 64 + mi * 16 + fq * 4;
        #pragma unroll
        for (int ni = 0; ni < 4; ++ni) {
            const int gcol = qn + (wave & 1) * 64 + ni * 16 + fr;
            #pragma unroll
            for (int r = 0; r < 4; ++r)
                atomicAdd(&G[(growb + r) * 256 + gcol], acc[mi][ni][r]);
        }
    }
    if (dosz) {
        #pragma unroll
        for (int p = 0; p < 8; ++p) {
            float s = sz[p];
            s += __shfl_xor(s, 1, 64);
            s += __shfl_xor(s, 2, 64);
            s += __shfl_xor(s, 4, 64);
            if ((lane & 7) == 0) atomicAdd(&Sz[p * 32 + cr], s);
        }
    }
}

// ============================================================ output: 128x128 dual GEMM, register-prefetch pipeline
__global__ __launch_bounds__(256, 2) void k_out2(
    const float* __restrict__ x, const float* __restrict__ sw,
    const float* __restrict__ pw_w, const float* __restrict__ res_w,
    const float* __restrict__ res_b, const float* __restrict__ sc_arr,
    const float* __restrict__ sh_arr, float* __restrict__ out)
{
    __shared__ __align__(16) unsigned short AsP[128 * ST];
    __shared__ __align__(16) unsigned short AsR[128 * ST];
    __shared__ __align__(16) unsigned short Bz[128 * ST];
    __shared__ __align__(16) unsigned short Bx[128 * ST];

    const int tid = threadIdx.x;
    const int lane = tid & 63, wave = tid >> 6;
    const int fr = lane & 15, fq = lane >> 4;
    const int wo = (wave >> 1) * 64;
    const int wl = (wave & 1) * 64;

    const int mt = blockIdx.x & 3;
    const int rest = blockIdx.x >> 2;
    const int lt = rest & 15;
    const int b = rest >> 4;
    const int o0 = mt * 128, l0 = lt * 128;

    const float w0 = sw[0], w1 = sw[1], w2 = sw[2];
    const float* xb = x + (size_t)b * kCin * kL;

    floatx4 accY[4][4], accR[4][4];
    #pragma unroll
    for (int mi = 0; mi < 4; ++mi)
        #pragma unroll
        for (int ni = 0; ni < 4; ++ni) {
            accY[mi][ni] = (floatx4){0.f, 0.f, 0.f, 0.f};
            accR[mi][ni] = (floatx4){0.f, 0.f, 0.f, 0.f};
        }

    const int sr = tid >> 1, sh_ = (tid & 1) * 16;
    const int c2 = (tid & 15) * 2;
    const int ll = (tid >> 4) * 8;
    const bool hasprv = (l0 + ll) >= 4;

    int aOff[4], bOff[4];
    #pragma unroll
    for (int mi = 0; mi < 4; ++mi) aOff[mi] = (wo + mi * 16 + fr) * ST + fq * 8;
    #pragma unroll
    for (int ni = 0; ni < 4; ++ni) bOff[ni] = (wl + ni * 16 + fr) * ST + fq * 8;

    // prefetch registers
    float4 wp[4], wr[4], xpa, xa0, xa1, xpb, xb0, xb1;
    auto LOAD = [&](int ks) {
        const int k0 = ks * BK;
        const float* sP = pw_w  + (size_t)(o0 + sr) * kCin + k0 + sh_;
        const float* sR = res_w + (size_t)(o0 + sr) * kCin + k0 + sh_;
        #pragma unroll
        for (int i = 0; i < 4; ++i) { wp[i] = ((const float4*)sP)[i]; wr[i] = ((const float4*)sR)[i]; }
        const float* base0 = xb + (size_t)(k0 + c2) * kL + l0 + ll;
        const float* base1 = base0 + kL;
        xpa = hasprv ? *(const float4*)(base0 - 4) : make_float4(0.f,0.f,0.f,0.f);
        xa0 = *(const float4*)(base0);
        xa1 = *(const float4*)(base0 + 4);
        xpb = hasprv ? *(const float4*)(base1 - 4) : make_float4(0.f,0.f,0.f,0.f);
        xb0 = *(const float4*)(base1);
        xb1 = *(const float4*)(base1 + 4);
    };
    auto PACKSTORE = [&]() {
        union { unsigned short u[8]; short8 v; } p0, p1, r0, r1;
        p0.u[0]=f2bf(wp[0].x); p0.u[1]=f2bf(wp[0].y); p0.u[2]=f2bf(wp[0].z); p0.u[3]=f2bf(wp[0].w);
        p0.u[4]=f2bf(wp[1].x); p0.u[5]=f2bf(wp[1].y); p0.u[6]=f2bf(wp[1].z); p0.u[7]=f2bf(wp[1].w);
        p1.u[0]=f2bf(wp[2].x); p1.u[1]=f2bf(wp[2].y); p1.u[2]=f2bf(wp[2].z); p1.u[3]=f2bf(wp[2].w);
        p1.u[4]=f2bf(wp[3].x); p1.u[5]=f2bf(wp[3].y); p1.u[6]=f2bf(wp[3].z); p1.u[7]=f2bf(wp[3].w);
        r0.u[0]=f2bf(wr[0].x); r0.u[1]=f2bf(wr[0].y); r0.u[2]=f2bf(wr[0].z); r0.u[3]=f2bf(wr[0].w);
        r0.u[4]=f2bf(wr[1].x); r0.u[5]=f2bf(wr[1].y); r0.u[6]=f2bf(wr[1].z); r0.u[7]=f2bf(wr[1].w);
        r1.u[0]=f2bf(wr[2].x); r1.u[1]=f2bf(wr[2].y); r1.u[2]=f2bf(wr[2].z); r1.u[3]=f2bf(wr[2].w);
        r1.u[4]=f2bf(wr[3].x); r1.u[5]=f2bf(wr[3].y); r1.u[6]=f2bf(wr[3].z); r1.u[7]=f2bf(wr[3].w);
        *(short8*)&AsP[sr * ST + sh_]     = p0.v;
        *(short8*)&AsP[sr * ST + sh_ + 8] = p1.v;
        *(short8*)&AsR[sr * ST + sh_]     = r0.v;
        *(short8*)&AsR[sr * ST + sh_ + 8] = r1.v;
        float A[12]  = {xpa.x,xpa.y,xpa.z,xpa.w, xa0.x,xa0.y,xa0.z,xa0.w, xa1.x,xa1.y,xa1.z,xa1.w};
        float Bv[12] = {xpb.x,xpb.y,xpb.z,xpb.w, xb0.x,xb0.y,xb0.z,xb0.w, xb1.x,xb1.y,xb1.z,xb1.w};
        #pragma unroll
        for (int j = 0; j < 8; ++j) {
            float zA = fmaf(w0, A[j],  fmaf(w1, A[j + 2],  w2 * A[j + 4]));
            float zB = fmaf(w0, Bv[j], fmaf(w1, Bv[j + 2], w2 * Bv[j + 4]));
            *(unsigned*)&Bz[(ll + j) * ST + c2] = pack2(zA, zB);
            *(unsigned*)&Bx[(ll + j) * ST + c2] = pack2(A[j + 4], Bv[j + 4]);
        }
    };

    LOAD(0);
    for (int ks = 0; ks < KSTEPS; ++ks) {
        PACKSTORE();
        __syncthreads();
        if (ks < KSTEPS - 1) LOAD(ks + 1);
        short8 vz[4], vx[4];
        #pragma unroll
        for (int ni = 0; ni < 4; ++ni) {
            vz[ni] = *(const short8*)&Bz[bOff[ni]];
            vx[ni] = *(const short8*)&Bx[bOff[ni]];
        }
        #pragma unroll
        for (int mi = 0; mi < 4; ++mi) {
            short8 ap = *(const short8*)&AsP[aOff[mi]];
            short8 ar = *(const short8*)&AsR[aOff[mi]];
            #pragma unroll
            for (int ni = 0; ni < 4; ++ni) {
                accY[mi][ni] = __builtin_amdgcn_mfma_f32_16x16x32_bf16(ap, vz[ni], accY[mi][ni], 0, 0, 0);
                accR[mi][ni] = __builtin_amdgcn_mfma_f32_16x16x32_bf16(ar, vx[ni], accR[mi][ni], 0, 0, 0);
            }
        }
        __syncthreads();
    }

    #pragma unroll
    for (int mi = 0; mi < 4; ++mi)
        #pragma unroll
        for (int r = 0; r < 4; ++r) {
            const int o = o0 + wo + mi * 16 + fq * 4 + r;
            const float sc = sc_arr[o], sh = sh_arr[o], rb = res_b[o];
            const size_t orow = ((size_t)b * kCout + o) * kL + l0 + wl + fr;
            #pragma unroll
            for (int ni = 0; ni < 4; ++ni) {
                float yn = fmaxf(fmaf(accY[mi][ni][r], sc, sh), 0.f);
                float rr = accR[mi][ni][r] + rb;
                out[orow + ni * 16] = fmaxf(yn + rr, 0.f);
            }
        }
}

extern "C" void kernel_launch(void* const* d_in, const int* in_sizes, int n_in,
                              void* d_out, int out_size, void* d_ws, size_t ws_size,
                              hipStream_t stream)
{
    (void)in_sizes; (void)n_in; (void)out_size;
    const float* x     = (const float*)d_in[0];
    const float* sw    = (const float*)d_in[1];
    const float* pw_w  = (const float*)d_in[2];
    const float* gamma = (const float*)d_in[4];
    const float* beta  = (const float*)d_in[5];
    const float* res_w = (const float*)d_in[6];
    const float* res_b = (const float*)d_in[7];
    float* out = (float*)d_out;
    float* wsf = (float*)d_ws;

    if (ws_size >= W2_BYTES) {
        hipMemsetAsync(wsf + W2_SZ, 0, 256 * sizeof(float), stream);
        k_prepc<<<256 * 32, 256, 0, stream>>>(x, sw, (unsigned short*)(wsf + W2_ZC), wsf + W2_SZ);
        k_gram2<<<512, 256, 0, stream>>>((const unsigned short*)(wsf + W2_ZC), wsf + W2_GPART);
        k_gred<<<256, 256, 0, stream>>>(wsf + W2_GPART, wsf + W2_G);
        k_bnp<<<kCout, 256, 0, stream>>>(wsf + W2_G, wsf + W2_SZ, pw_w, gamma, beta,
                                         wsf + W2_SC, wsf + W2_SH);
        k_out2<<<GRID_OUT, 256, 0, stream>>>(x, sw, pw_w, res_w, res_b,
                                             wsf + W2_SC, wsf + W2_SH, out);
    } else {
        hipMemsetAsync(wsf, 0, (WF_SC) * sizeof(float), stream);
        k_gram_fb<<<512, 256, 0, stream>>>(x, sw, wsf + WF_G, wsf + WF_SZ);
        k_bnp<<<kCout, 256, 0, stream>>>(wsf + WF_G, wsf + WF_SZ, pw_w, gamma, beta,
                                         wsf + WF_SC, wsf + WF_SH);
        k_out2<<<GRID_OUT, 256, 0, stream>>>(x, sw, pw_w, res_w, res_b,
                                             wsf + WF_SC, wsf + WF_SH, out);
    }
}